// Round 3
// baseline (125561.816 us; speedup 1.0000x reference)
//
#include <hip/hip_runtime.h>
#include <cstdint>
#include <cstddef>

#define VOCAB_N 50257
#define NPAD    50304          // padded row stride for logits
#define DIM     1024
#define BSZ_N   32
#define BEAM_N  4
#define BB      128            // BSZ * BEAM
#define L_N     66             // MAXLEN + 2
#define SLEN_N  65             // MAXLEN + 1
#define MAXLEN_N 64
#define PAD_T   1
#define EOS_T   2
#define NEGV    (-1e9f)
#define SENTV   (-3.402823466e38f)
#define PW_BLOCK 128

// ---------------- init state ----------------
__global__ void k_init(int* __restrict__ tokens, float* __restrict__ scores,
                       int* __restrict__ fin_tok, float* __restrict__ fin_sc) {
    int i = blockIdx.x * blockDim.x + threadIdx.x;
    int st = gridDim.x * blockDim.x;
    for (int k = i; k < BB * L_N; k += st) tokens[k] = ((k % L_N) == 0) ? EOS_T : PAD_T;
    for (int k = i; k < BB * SLEN_N; k += st) scores[k] = 0.f;
    for (int k = i; k < BB * L_N; k += st) fin_tok[k] = 0;
    for (int k = i; k < BB; k += st) fin_sc[k] = NEGV;
}

// ---------------- gather h^T (f32, single rounding like np) ----------------
__global__ __launch_bounds__(256) void k_gather(const float* __restrict__ emb,
                                                const float* __restrict__ pos_emb,
                                                const int* __restrict__ tokens,
                                                float* __restrict__ hT, int step) {
    int idx = blockIdx.x * 256 + threadIdx.x;     // 131072 total
    int d = idx >> 7;
    int row = idx & 127;
    int tok = tokens[row * L_N + step];
    hT[idx] = emb[(size_t)tok * DIM + d] + pos_emb[(size_t)step * DIM + d];
}

// ---------------- GEMM: f32 in, f64 accumulate, f32 out ----------------
#define KSTEP 16
#define FMA_ROW(i, a)                                                     \
    acc[i][0] = fma((double)(a), w0, acc[i][0]);                          \
    acc[i][1] = fma((double)(a), w1, acc[i][1]);                          \
    acc[i][2] = fma((double)(a), w2, acc[i][2]);                          \
    acc[i][3] = fma((double)(a), w3, acc[i][3]);

__global__ __launch_bounds__(256) void k_gemm(const float* __restrict__ W,
                                              const float* __restrict__ hT,
                                              float* __restrict__ logits) {
    __shared__ __align__(16) float Hs[KSTEP][128];
    __shared__ __align__(16) float Ws[KSTEP][64];
    const int tid = threadIdx.x;
    const int n0 = blockIdx.x * 64;
    const int n4 = (tid & 15) * 4;
    const int m8 = (tid >> 4) * 8;
    const int lr  = tid >> 4;
    const int lcW = (tid & 15) * 4;
    const int lcH = (tid & 15) * 8;
    double acc[8][4];
#pragma unroll
    for (int i = 0; i < 8; ++i)
#pragma unroll
        for (int j = 0; j < 4; ++j) acc[i][j] = 0.0;

    const bool full = (n0 + 64 <= VOCAB_N);
    for (int k0 = 0; k0 < DIM; k0 += KSTEP) {
        {
            const float* wp = W + (size_t)(k0 + lr) * VOCAB_N + n0 + lcW;
            float4 wv4;
            if (full) {
                wv4 = *(const float4*)wp;
            } else {
                wv4.x = (n0 + lcW + 0 < VOCAB_N) ? wp[0] : 0.f;
                wv4.y = (n0 + lcW + 1 < VOCAB_N) ? wp[1] : 0.f;
                wv4.z = (n0 + lcW + 2 < VOCAB_N) ? wp[2] : 0.f;
                wv4.w = (n0 + lcW + 3 < VOCAB_N) ? wp[3] : 0.f;
            }
            *(float4*)&Ws[lr][lcW] = wv4;
        }
        {
            const float* hp = hT + (size_t)(k0 + lr) * BB + lcH;
            *(float4*)&Hs[lr][lcH]     = *(const float4*)hp;
            *(float4*)&Hs[lr][lcH + 4] = *(const float4*)(hp + 4);
        }
        __syncthreads();
#pragma unroll
        for (int kk = 0; kk < KSTEP; ++kk) {
            const float4 wv = *(const float4*)&Ws[kk][n4];
            const double w0 = (double)wv.x, w1 = (double)wv.y;
            const double w2 = (double)wv.z, w3 = (double)wv.w;
            const float4 h0 = *(const float4*)&Hs[kk][m8];
            const float4 h1 = *(const float4*)&Hs[kk][m8 + 4];
            FMA_ROW(0, h0.x) FMA_ROW(1, h0.y) FMA_ROW(2, h0.z) FMA_ROW(3, h0.w)
            FMA_ROW(4, h1.x) FMA_ROW(5, h1.y) FMA_ROW(6, h1.z) FMA_ROW(7, h1.w)
        }
        __syncthreads();
    }
#pragma unroll
    for (int i = 0; i < 8; ++i) {
        float4 o;
        o.x = (float)acc[i][0]; o.y = (float)acc[i][1];
        o.z = (float)acc[i][2]; o.w = (float)acc[i][3];
        *(float4*)&logits[(size_t)(m8 + i) * NPAD + n0 + n4] = o;
    }
}

// ---------------- rowstats: exact max + numpy-exact f32 pairwise LSE ----------------
__global__ __launch_bounds__(256) void k_rowstats(const float* __restrict__ logits,
                                                  float* __restrict__ rmax,
                                                  float* __restrict__ rlse) {
    const int row = blockIdx.x, tid = threadIdx.x;
    const float* x = logits + (size_t)row * NPAD;

    // exact max (order-independent)
    float m = SENTV;
    for (int v = tid * 4; v + 3 < VOCAB_N; v += 1024) {
        const float4 t = *(const float4*)(x + v);
        m = fmaxf(m, fmaxf(fmaxf(t.x, t.y), fmaxf(t.z, t.w)));
    }
    if (tid == 0) m = fmaxf(m, x[VOCAB_N - 1]);
    __shared__ float sm[256];
    sm[tid] = m; __syncthreads();
    for (int s = 128; s > 0; s >>= 1) {
        if (tid < s) sm[tid] = fmaxf(sm[tid], sm[tid + s]);
        __syncthreads();
    }
    const float mrow = sm[0];
    __syncthreads();

    // numpy pairwise_sum tree: enumerate leaves (left-to-right)
    __shared__ int ls[1024];
    __shared__ short ln[1024];
    __shared__ float lsum[1024];
    __shared__ int nleaf_s;
    if (tid == 0) {
        int st_s[40], st_n[40];
        st_s[0] = 0; st_n[0] = VOCAB_N;
        int sp = 1, cnt = 0;
        while (sp > 0) {
            --sp;
            int s = st_s[sp], n = st_n[sp];
            while (n > PW_BLOCK) {
                int L = (n >> 1); L -= (L & 7);
                st_s[sp] = s + L; st_n[sp] = n - L; ++sp;  // push right
                n = L;                                     // continue left
            }
            ls[cnt] = s; ln[cnt] = (short)n; ++cnt;
        }
        nleaf_s = cnt;
    }
    __syncthreads();
    const int nleaf = nleaf_s;

    // leaf sums: numpy's <=128-block 8-accumulator scheme, f32 exp terms
    for (int leaf = tid; leaf < nleaf; leaf += 256) {
        const int s = ls[leaf];
        const int n = (int)ln[leaf];
        float res;
        if (n < 8) {
            res = 0.f;
            for (int i = 0; i < n; ++i) res += expf(x[s + i] - mrow);
        } else {
            float r0 = expf(x[s + 0] - mrow), r1 = expf(x[s + 1] - mrow);
            float r2 = expf(x[s + 2] - mrow), r3 = expf(x[s + 3] - mrow);
            float r4 = expf(x[s + 4] - mrow), r5 = expf(x[s + 5] - mrow);
            float r6 = expf(x[s + 6] - mrow), r7 = expf(x[s + 7] - mrow);
            int i = 8;
            const int lim = n - (n & 7);
            for (; i < lim; i += 8) {
                r0 += expf(x[s + i + 0] - mrow); r1 += expf(x[s + i + 1] - mrow);
                r2 += expf(x[s + i + 2] - mrow); r3 += expf(x[s + i + 3] - mrow);
                r4 += expf(x[s + i + 4] - mrow); r5 += expf(x[s + i + 5] - mrow);
                r6 += expf(x[s + i + 6] - mrow); r7 += expf(x[s + i + 7] - mrow);
            }
            res = ((r0 + r1) + (r2 + r3)) + ((r4 + r5) + (r6 + r7));
            for (; i < n; ++i) res += expf(x[s + i] - mrow);
        }
        lsum[leaf] = res;
    }
    __syncthreads();

    // postorder combine with numpy's recursion structure (f32 adds)
    if (tid == 0) {
        int fn[28]; signed char fst[28]; float fl[28];
        fn[0] = VOCAB_N; fst[0] = 0;
        int sp = 1, li = 0;
        float ret = 0.f;
        while (sp > 0) {
            int n = fn[sp - 1];
            if (n <= PW_BLOCK) { ret = lsum[li++]; --sp; continue; }
            int L = (n >> 1); L -= (L & 7);
            signed char st = fst[sp - 1];
            if (st == 0)      { fst[sp - 1] = 1; fn[sp] = L;     fst[sp] = 0; ++sp; }
            else if (st == 1) { fl[sp - 1] = ret; fst[sp - 1] = 2; fn[sp] = n - L; fst[sp] = 0; ++sp; }
            else              { ret = fl[sp - 1] + ret; --sp; }
        }
        rmax[row] = mrow;
        rlse[row] = (float)log((double)ret);   // correctly-rounded f32 log
    }
}

// ---------------- per-thread sorted top-8 insert (stable ties by index) ----------------
__device__ __forceinline__ void ins8(float v, int ix, float tv[8], int tix[8]) {
#pragma unroll
    for (int p = 0; p < 8; ++p) {
        if (v > tv[p] || (v == tv[p] && ix < tix[p])) {
            float ov = tv[p]; int oi = tix[p];
            tv[p] = v; tix[p] = ix; v = ov; ix = oi;
        }
    }
}

// ---------------- top-8 per sentence + literal beam bookkeeping ----------------
__global__ __launch_bounds__(256) void k_topk(const float* __restrict__ logits,
                                              const float* __restrict__ rmax,
                                              const float* __restrict__ rlse,
                                              int* __restrict__ tokens,
                                              float* __restrict__ scores,
                                              int* __restrict__ fin_tok,
                                              float* __restrict__ fin_sc,
                                              int step) {
    const int sent = blockIdx.x;
    const int tid = threadIdx.x;
    float tv[8]; int tix[8];
#pragma unroll
    for (int p = 0; p < 8; ++p) { tv[p] = SENTV; tix[p] = 0x7fffffff; }

    const int rN = (step == 0) ? 1 : BEAM_N;
    for (int r = 0; r < rN; ++r) {
        const int row = sent * BEAM_N + r;
        const float rm = rmax[row], rl = rlse[row];
        const float prev = (step == 0) ? 0.f : scores[row * SLEN_N + step - 1];
        const float* x = logits + (size_t)row * NPAD;
        const int base = r * VOCAB_N;
        for (int v = tid * 4; v + 3 < VOCAB_N; v += 1024) {
            const float4 t = *(const float4*)(x + v);
            float va[4] = {t.x, t.y, t.z, t.w};
#pragma unroll
            for (int u = 0; u < 4; ++u) {
                const int tk = v + u;
                if (tk == PAD_T) continue;
                const float val = ((va[u] - rm) - rl) + prev;  // f32, ref association
                if (val >= tv[7]) ins8(val, base + tk, tv, tix);
            }
        }
        if (tid == 0) {
            const int tk = VOCAB_N - 1;
            const float val = ((x[tk] - rm) - rl) + prev;
            if (val >= tv[7]) ins8(val, base + tk, tv, tix);
        }
    }

    // block merge: 8 passes of stable argmax over 2048 entries
    __shared__ float sval[2048];
    __shared__ int   sidx[2048];
#pragma unroll
    for (int p = 0; p < 8; ++p) { sval[tid * 8 + p] = tv[p]; sidx[tid * 8 + p] = tix[p]; }
    __shared__ float rv[256]; __shared__ int ri[256]; __shared__ int rs[256];
    __shared__ float cand_sc[8]; __shared__ int cand_flat[8];
    __syncthreads();
    for (int pass = 0; pass < 8; ++pass) {
        float bv = SENTV; int bi = 0x7fffffff; int bs = -1;
        for (int k = tid; k < 2048; k += 256) {
            const float v = sval[k]; const int ix = sidx[k];
            if (v > bv || (v == bv && ix < bi)) { bv = v; bi = ix; bs = k; }
        }
        rv[tid] = bv; ri[tid] = bi; rs[tid] = bs;
        __syncthreads();
        for (int s = 128; s > 0; s >>= 1) {
            if (tid < s) {
                if (rv[tid + s] > rv[tid] ||
                    (rv[tid + s] == rv[tid] && ri[tid + s] < ri[tid])) {
                    rv[tid] = rv[tid + s]; ri[tid] = ri[tid + s]; rs[tid] = rs[tid + s];
                }
            }
            __syncthreads();
        }
        if (tid == 0) {
            cand_sc[pass] = rv[0]; cand_flat[pass] = ri[0];
            sval[rs[0]] = SENTV; sidx[rs[0]] = 0x7fffffff;
        }
        __syncthreads();
    }

    // preload sentence state into LDS (parallel)
    __shared__ int   cur_tok[BEAM_N * L_N];
    __shared__ int   cur_fin[BEAM_N * L_N];
    __shared__ float cur_sc[BEAM_N * SLEN_N];
    for (int e = tid; e < BEAM_N * L_N; e += 256) {
        cur_tok[e] = tokens[sent * (BEAM_N * L_N) + e];
        cur_fin[e] = fin_tok[sent * (BEAM_N * L_N) + e];
    }
    for (int e = tid; e < BEAM_N * SLEN_N; e += 256)
        cur_sc[e] = scores[sent * (BEAM_N * SLEN_N) + e];
    __syncthreads();

    // literal single-thread bookkeeping (mirrors the reference text)
    __shared__ int   tmp_fin[BEAM_N * L_N];
    __shared__ int   tmp_tok[BEAM_N * L_N];
    __shared__ float tmp_sc[BEAM_N * SLEN_N];
    __shared__ float nfin_s[BEAM_N];
    if (tid == 0) {
        int cb[8], ct[8];
        for (int j = 0; j < 8; ++j) {
            cb[j] = cand_flat[j] / VOCAB_N;
            ct[j] = cand_flat[j] % VOCAB_N;
        }
        // finalize merge: all_sc = [fin_sc, eos_norm]
        float allsc[8];
        for (int j = 0; j < 4; ++j) allsc[j] = fin_sc[sent * BEAM_N + j];
        for (int j = 0; j < 4; ++j)
            allsc[4 + j] = (ct[j] == EOS_T) ? (cand_sc[j] / (float)(step + 1)) : NEGV;
        int fsel[4]; float nfin[4];
        bool used[8] = {false,false,false,false,false,false,false,false};
        for (int b = 0; b < 4; ++b) {
            int best = -1; float bvv = 0.f;
            for (int j = 0; j < 8; ++j) {
                if (used[j]) continue;
                if (best < 0 || allsc[j] > bvv) { best = j; bvv = allsc[j]; }
            }
            used[best] = true; fsel[b] = best; nfin[b] = bvv;
        }
        // new fin_tok
        for (int b = 0; b < 4; ++b) {
            const int s = fsel[b];
            if (s < 4) {
                for (int p = 0; p < L_N; ++p) tmp_fin[b * L_N + p] = cur_fin[s * L_N + p];
            } else {
                const int bm = cb[s - 4];
                for (int p = 0; p < L_N; ++p)
                    tmp_fin[b * L_N + p] = (p == step + 1) ? EOS_T : cur_tok[bm * L_N + p];
            }
        }
        // active: first 4 non-EOS candidates in order
        int ab[4], atk[4]; float asc[4]; int na = 0;
        for (int j = 0; j < 8 && na < 4; ++j) {
            if (ct[j] != EOS_T) { ab[na] = cb[j]; atk[na] = ct[j]; asc[na] = cand_sc[j]; ++na; }
        }
        // reorder + append
        for (int b = 0; b < 4; ++b) {
            const int bm = ab[b];
            for (int p = 0; p < L_N; ++p)
                tmp_tok[b * L_N + p] = (p == step + 1) ? atk[b] : cur_tok[bm * L_N + p];
            for (int p = 0; p < SLEN_N; ++p)
                tmp_sc[b * SLEN_N + p] = (p == step) ? asc[b] : cur_sc[bm * SLEN_N + p];
        }
        for (int b = 0; b < 4; ++b) nfin_s[b] = nfin[b];
    }
    __syncthreads();

    // parallel writeback
    for (int e = tid; e < BEAM_N * L_N; e += 256) {
        fin_tok[sent * (BEAM_N * L_N) + e] = tmp_fin[e];
        tokens[sent * (BEAM_N * L_N) + e]  = tmp_tok[e];
    }
    for (int e = tid; e < BEAM_N * SLEN_N; e += 256)
        scores[sent * (BEAM_N * SLEN_N) + e] = tmp_sc[e];
    if (tid < 4) fin_sc[sent * BEAM_N + tid] = nfin_s[tid];
}

// ---------------- final forced-EOS merge + output write ----------------
__global__ __launch_bounds__(256) void k_final(const float* __restrict__ logits,
                                               const float* __restrict__ rmax,
                                               const float* __restrict__ rlse,
                                               const int* __restrict__ tokens,
                                               const float* __restrict__ scores,
                                               const int* __restrict__ fin_tok,
                                               const float* __restrict__ fin_sc,
                                               float* __restrict__ out) {
    const int sent = blockIdx.x;
    const int tid = threadIdx.x;
    __shared__ int fsel_s[4]; __shared__ float nfin_s[4];
    if (tid == 0) {
        float allsc[8];
        for (int r = 0; r < 4; ++r) {
            const int row = sent * BEAM_N + r;
            const float lpE = ((logits[(size_t)row * NPAD + EOS_T] - rmax[row]) - rlse[row]);
            allsc[r] = fin_sc[sent * BEAM_N + r];
            allsc[4 + r] = (scores[row * SLEN_N + (MAXLEN_N - 1)] + lpE) / 65.0f;
        }
        bool used[8] = {false,false,false,false,false,false,false,false};
        for (int b = 0; b < 4; ++b) {
            int best = -1; float bvv = 0.f;
            for (int j = 0; j < 8; ++j) {
                if (used[j]) continue;
                if (best < 0 || allsc[j] > bvv) { best = j; bvv = allsc[j]; }
            }
            used[best] = true; fsel_s[b] = best; nfin_s[b] = bvv;
        }
    }
    __syncthreads();
    for (int e = tid; e < BEAM_N * L_N; e += 256) {
        const int b = e / L_N, p = e % L_N;
        const int s = fsel_s[b]; int valt;
        if (s < 4) {
            valt = fin_tok[(sent * BEAM_N + s) * L_N + p];
        } else {
            const int r = s - 4;
            valt = (p == MAXLEN_N + 1) ? EOS_T : tokens[(sent * BEAM_N + r) * L_N + p];
        }
        out[(size_t)(sent * BEAM_N + b) * L_N + p] = (float)valt;
    }
    if (tid < 4) out[BSZ_N * BEAM_N * L_N + sent * BEAM_N + tid] = nfin_s[tid];
}

extern "C" void kernel_launch(void* const* d_in, const int* in_sizes, int n_in,
                              void* d_out, int out_size, void* d_ws, size_t ws_size,
                              hipStream_t stream) {
    const float* emb = (const float*)d_in[0];
    const float* W   = (const float*)d_in[1];
    const float* pos = (const float*)d_in[2];
    float* out = (float*)d_out;

    char* w = (char*)d_ws;
    float* hT     = (float*)w;  w += (size_t)DIM * BB * 4;        // 512 KB
    float* logits = (float*)w;  w += (size_t)BB * NPAD * 4;       // 25.76 MB
    float* rmaxb  = (float*)w;  w += BB * 4;
    float* rlseb  = (float*)w;  w += BB * 4;
    int*   tokens = (int*)w;    w += BB * L_N * 4;
    float* scores = (float*)w;  w += BB * SLEN_N * 4;
    int*   ftok   = (int*)w;    w += BB * L_N * 4;
    float* fsc    = (float*)w;  w += BB * 4;

    k_init<<<32, 256, 0, stream>>>(tokens, scores, ftok, fsc);
    for (int s = 0; s < MAXLEN_N; ++s) {
        k_gather<<<(DIM * BB) / 256, 256, 0, stream>>>(emb, pos, tokens, hT, s);
        k_gemm<<<NPAD / 64, 256, 0, stream>>>(W, hT, logits);
        k_rowstats<<<BB, 256, 0, stream>>>(logits, rmaxb, rlseb);
        k_topk<<<BSZ_N, 256, 0, stream>>>(logits, rmaxb, rlseb, tokens, scores, ftok, fsc, s);
    }
    k_gather<<<(DIM * BB) / 256, 256, 0, stream>>>(emb, pos, tokens, hT, MAXLEN_N);
    k_gemm<<<NPAD / 64, 256, 0, stream>>>(W, hT, logits);
    k_rowstats<<<BB, 256, 0, stream>>>(logits, rmaxb, rlseb);
    k_final<<<BSZ_N, 256, 0, stream>>>(logits, rmaxb, rlseb, tokens, scores, ftok, fsc, out);
}

// Round 4
// 113381.653 us; speedup vs baseline: 1.1074x; 1.1074x over previous
//
#include <hip/hip_runtime.h>
#include <cstdint>
#include <cstddef>

#define VOCAB_N 50257
#define NPAD    50304          // padded row stride for logits
#define DIM     1024
#define BSZ_N   32
#define BEAM_N  4
#define BB      128            // BSZ * BEAM
#define L_N     66             // MAXLEN + 2
#define SLEN_N  65             // MAXLEN + 1
#define MAXLEN_N 64
#define PAD_T   1
#define EOS_T   2
#define NEGV    (-1e9f)
#define SENTV   (-3.402823466e38f)
#define PW_BLOCK 128

// ---------------- init state ----------------
__global__ void k_init(int* __restrict__ tokens, float* __restrict__ scores,
                       int* __restrict__ fin_tok, float* __restrict__ fin_sc) {
    int i = blockIdx.x * blockDim.x + threadIdx.x;
    int st = gridDim.x * blockDim.x;
    for (int k = i; k < BB * L_N; k += st) tokens[k] = ((k % L_N) == 0) ? EOS_T : PAD_T;
    for (int k = i; k < BB * SLEN_N; k += st) scores[k] = 0.f;
    for (int k = i; k < BB * L_N; k += st) fin_tok[k] = 0;
    for (int k = i; k < BB; k += st) fin_sc[k] = NEGV;
}

// ---------------- gather h^T (f32, single rounding like np) ----------------
__global__ __launch_bounds__(256) void k_gather(const float* __restrict__ emb,
                                                const float* __restrict__ pos_emb,
                                                const int* __restrict__ tokens,
                                                float* __restrict__ hT, int step) {
    int idx = blockIdx.x * 256 + threadIdx.x;     // 131072 total
    int d = idx >> 7;
    int row = idx & 127;
    int tok = tokens[row * L_N + step];
    hT[idx] = emb[(size_t)tok * DIM + d] + pos_emb[(size_t)step * DIM + d];
}

// ---------------- GEMM (f32, r1 realization): logits[m][n] = sum_d hT[d][m]*W[d][n] ----------------
#define KSTEP 16
#define FMA_ROW(i, a)                                           \
    acc[i][0] += (a) * wv.x; acc[i][1] += (a) * wv.y;           \
    acc[i][2] += (a) * wv.z; acc[i][3] += (a) * wv.w;

__global__ __launch_bounds__(256) void k_gemm(const float* __restrict__ W,
                                              const float* __restrict__ hT,
                                              float* __restrict__ logits) {
    __shared__ __align__(16) float Hs[KSTEP][128];
    __shared__ __align__(16) float Ws[KSTEP][64];
    const int tid = threadIdx.x;
    const int n0 = blockIdx.x * 64;
    const int n4 = (tid & 15) * 4;
    const int m8 = (tid >> 4) * 8;
    const int lr  = tid >> 4;          // 0..15: k-row for staging
    const int lcW = (tid & 15) * 4;
    const int lcH = (tid & 15) * 8;
    float acc[8][4];
#pragma unroll
    for (int i = 0; i < 8; ++i)
#pragma unroll
        for (int j = 0; j < 4; ++j) acc[i][j] = 0.f;

    const bool full = (n0 + 64 <= VOCAB_N);
    for (int k0 = 0; k0 < DIM; k0 += KSTEP) {
        // stage W tile [KSTEP][64]
        {
            const float* wp = W + (size_t)(k0 + lr) * VOCAB_N + n0 + lcW;
            float4 wv4;
            if (full) {
                wv4 = *(const float4*)wp;
            } else {
                wv4.x = (n0 + lcW + 0 < VOCAB_N) ? wp[0] : 0.f;
                wv4.y = (n0 + lcW + 1 < VOCAB_N) ? wp[1] : 0.f;
                wv4.z = (n0 + lcW + 2 < VOCAB_N) ? wp[2] : 0.f;
                wv4.w = (n0 + lcW + 3 < VOCAB_N) ? wp[3] : 0.f;
            }
            *(float4*)&Ws[lr][lcW] = wv4;
        }
        // stage H tile [KSTEP][128]
        {
            const float* hp = hT + (size_t)(k0 + lr) * BB + lcH;
            *(float4*)&Hs[lr][lcH]     = *(const float4*)hp;
            *(float4*)&Hs[lr][lcH + 4] = *(const float4*)(hp + 4);
        }
        __syncthreads();
#pragma unroll
        for (int kk = 0; kk < KSTEP; ++kk) {
            const float4 wv = *(const float4*)&Ws[kk][n4];
            const float4 h0 = *(const float4*)&Hs[kk][m8];
            const float4 h1 = *(const float4*)&Hs[kk][m8 + 4];
            FMA_ROW(0, h0.x) FMA_ROW(1, h0.y) FMA_ROW(2, h0.z) FMA_ROW(3, h0.w)
            FMA_ROW(4, h1.x) FMA_ROW(5, h1.y) FMA_ROW(6, h1.z) FMA_ROW(7, h1.w)
        }
        __syncthreads();
    }
#pragma unroll
    for (int i = 0; i < 8; ++i) {
        float4 o; o.x = acc[i][0]; o.y = acc[i][1]; o.z = acc[i][2]; o.w = acc[i][3];
        *(float4*)&logits[(size_t)(m8 + i) * NPAD + n0 + n4] = o;
    }
}

// ---------------- rowstats: exact max + numpy-exact f32 pairwise LSE ----------------
__global__ __launch_bounds__(256) void k_rowstats(const float* __restrict__ logits,
                                                  float* __restrict__ rmax,
                                                  float* __restrict__ rlse) {
    const int row = blockIdx.x, tid = threadIdx.x;
    const float* x = logits + (size_t)row * NPAD;

    // exact max (order-independent)
    float m = SENTV;
    for (int v = tid * 4; v + 3 < VOCAB_N; v += 1024) {
        const float4 t = *(const float4*)(x + v);
        m = fmaxf(m, fmaxf(fmaxf(t.x, t.y), fmaxf(t.z, t.w)));
    }
    if (tid == 0) m = fmaxf(m, x[VOCAB_N - 1]);
    __shared__ float sm[256];
    sm[tid] = m; __syncthreads();
    for (int s = 128; s > 0; s >>= 1) {
        if (tid < s) sm[tid] = fmaxf(sm[tid], sm[tid + s]);
        __syncthreads();
    }
    const float mrow = sm[0];
    __syncthreads();

    // numpy pairwise_sum tree: enumerate leaves (left-to-right)
    __shared__ int ls[1024];
    __shared__ short ln[1024];
    __shared__ float lsum[1024];
    __shared__ int nleaf_s;
    if (tid == 0) {
        int st_s[40], st_n[40];
        st_s[0] = 0; st_n[0] = VOCAB_N;
        int sp = 1, cnt = 0;
        while (sp > 0) {
            --sp;
            int s = st_s[sp], n = st_n[sp];
            while (n > PW_BLOCK) {
                int L = (n >> 1); L -= (L & 7);
                st_s[sp] = s + L; st_n[sp] = n - L; ++sp;  // push right
                n = L;                                     // continue left
            }
            ls[cnt] = s; ln[cnt] = (short)n; ++cnt;
        }
        nleaf_s = cnt;
    }
    __syncthreads();
    const int nleaf = nleaf_s;

    // leaf sums: numpy's <=128-block 8-accumulator scheme, f32 exp terms
    for (int leaf = tid; leaf < nleaf; leaf += 256) {
        const int s = ls[leaf];
        const int n = (int)ln[leaf];
        float res;
        if (n < 8) {
            res = 0.f;
            for (int i = 0; i < n; ++i) res += expf(x[s + i] - mrow);
        } else {
            float r0 = expf(x[s + 0] - mrow), r1 = expf(x[s + 1] - mrow);
            float r2 = expf(x[s + 2] - mrow), r3 = expf(x[s + 3] - mrow);
            float r4 = expf(x[s + 4] - mrow), r5 = expf(x[s + 5] - mrow);
            float r6 = expf(x[s + 6] - mrow), r7 = expf(x[s + 7] - mrow);
            int i = 8;
            const int lim = n - (n & 7);
            for (; i < lim; i += 8) {
                r0 += expf(x[s + i + 0] - mrow); r1 += expf(x[s + i + 1] - mrow);
                r2 += expf(x[s + i + 2] - mrow); r3 += expf(x[s + i + 3] - mrow);
                r4 += expf(x[s + i + 4] - mrow); r5 += expf(x[s + i + 5] - mrow);
                r6 += expf(x[s + i + 6] - mrow); r7 += expf(x[s + i + 7] - mrow);
            }
            res = ((r0 + r1) + (r2 + r3)) + ((r4 + r5) + (r6 + r7));
            for (; i < n; ++i) res += expf(x[s + i] - mrow);
        }
        lsum[leaf] = res;
    }
    __syncthreads();

    // postorder combine with numpy's recursion structure (f32 adds)
    if (tid == 0) {
        int fn[28]; signed char fst[28]; float fl[28];
        fn[0] = VOCAB_N; fst[0] = 0;
        int sp = 1, li = 0;
        float ret = 0.f;
        while (sp > 0) {
            int n = fn[sp - 1];
            if (n <= PW_BLOCK) { ret = lsum[li++]; --sp; continue; }
            int L = (n >> 1); L -= (L & 7);
            signed char st = fst[sp - 1];
            if (st == 0)      { fst[sp - 1] = 1; fn[sp] = L;     fst[sp] = 0; ++sp; }
            else if (st == 1) { fl[sp - 1] = ret; fst[sp - 1] = 2; fn[sp] = n - L; fst[sp] = 0; ++sp; }
            else              { ret = fl[sp - 1] + ret; --sp; }
        }
        rmax[row] = mrow;
        rlse[row] = (float)log((double)ret);   // correctly-rounded f32 log
    }
}

// ---------------- per-thread sorted top-8 insert (stable ties by index) ----------------
__device__ __forceinline__ void ins8(float v, int ix, float tv[8], int tix[8]) {
#pragma unroll
    for (int p = 0; p < 8; ++p) {
        if (v > tv[p] || (v == tv[p] && ix < tix[p])) {
            float ov = tv[p]; int oi = tix[p];
            tv[p] = v; tix[p] = ix; v = ov; ix = oi;
        }
    }
}

// ---------------- top-8 per sentence + literal beam bookkeeping ----------------
__global__ __launch_bounds__(256) void k_topk(const float* __restrict__ logits,
                                              const float* __restrict__ rmax,
                                              const float* __restrict__ rlse,
                                              int* __restrict__ tokens,
                                              float* __restrict__ scores,
                                              int* __restrict__ fin_tok,
                                              float* __restrict__ fin_sc,
                                              int step) {
    const int sent = blockIdx.x;
    const int tid = threadIdx.x;
    float tv[8]; int tix[8];
#pragma unroll
    for (int p = 0; p < 8; ++p) { tv[p] = SENTV; tix[p] = 0x7fffffff; }

    const int rN = (step == 0) ? 1 : BEAM_N;
    for (int r = 0; r < rN; ++r) {
        const int row = sent * BEAM_N + r;
        const float rm = rmax[row], rl = rlse[row];
        const float prev = (step == 0) ? 0.f : scores[row * SLEN_N + step - 1];
        const float* x = logits + (size_t)row * NPAD;
        const int base = r * VOCAB_N;
        for (int v = tid * 4; v + 3 < VOCAB_N; v += 1024) {
            const float4 t = *(const float4*)(x + v);
            float va[4] = {t.x, t.y, t.z, t.w};
#pragma unroll
            for (int u = 0; u < 4; ++u) {
                const int tk = v + u;
                if (tk == PAD_T) continue;
                const float val = ((va[u] - rm) - rl) + prev;  // f32, ref association
                if (val >= tv[7]) ins8(val, base + tk, tv, tix);
            }
        }
        if (tid == 0) {
            const int tk = VOCAB_N - 1;
            const float val = ((x[tk] - rm) - rl) + prev;
            if (val >= tv[7]) ins8(val, base + tk, tv, tix);
        }
    }

    // block merge: 8 passes of stable argmax over 2048 entries
    __shared__ float sval[2048];
    __shared__ int   sidx[2048];
#pragma unroll
    for (int p = 0; p < 8; ++p) { sval[tid * 8 + p] = tv[p]; sidx[tid * 8 + p] = tix[p]; }
    __shared__ float rv[256]; __shared__ int ri[256]; __shared__ int rs[256];
    __shared__ float cand_sc[8]; __shared__ int cand_flat[8];
    __syncthreads();
    for (int pass = 0; pass < 8; ++pass) {
        float bv = SENTV; int bi = 0x7fffffff; int bs = -1;
        for (int k = tid; k < 2048; k += 256) {
            const float v = sval[k]; const int ix = sidx[k];
            if (v > bv || (v == bv && ix < bi)) { bv = v; bi = ix; bs = k; }
        }
        rv[tid] = bv; ri[tid] = bi; rs[tid] = bs;
        __syncthreads();
        for (int s = 128; s > 0; s >>= 1) {
            if (tid < s) {
                if (rv[tid + s] > rv[tid] ||
                    (rv[tid + s] == rv[tid] && ri[tid + s] < ri[tid])) {
                    rv[tid] = rv[tid + s]; ri[tid] = ri[tid + s]; rs[tid] = rs[tid + s];
                }
            }
            __syncthreads();
        }
        if (tid == 0) {
            cand_sc[pass] = rv[0]; cand_flat[pass] = ri[0];
            sval[rs[0]] = SENTV; sidx[rs[0]] = 0x7fffffff;
        }
        __syncthreads();
    }

    // preload sentence state into LDS (parallel)
    __shared__ int   cur_tok[BEAM_N * L_N];
    __shared__ int   cur_fin[BEAM_N * L_N];
    __shared__ float cur_sc[BEAM_N * SLEN_N];
    for (int e = tid; e < BEAM_N * L_N; e += 256) {
        cur_tok[e] = tokens[sent * (BEAM_N * L_N) + e];
        cur_fin[e] = fin_tok[sent * (BEAM_N * L_N) + e];
    }
    for (int e = tid; e < BEAM_N * SLEN_N; e += 256)
        cur_sc[e] = scores[sent * (BEAM_N * SLEN_N) + e];
    __syncthreads();

    // literal single-thread bookkeeping (mirrors the reference text)
    __shared__ int   tmp_fin[BEAM_N * L_N];
    __shared__ int   tmp_tok[BEAM_N * L_N];
    __shared__ float tmp_sc[BEAM_N * SLEN_N];
    __shared__ float nfin_s[BEAM_N];
    if (tid == 0) {
        int cb[8], ct[8];
        for (int j = 0; j < 8; ++j) {
            cb[j] = cand_flat[j] / VOCAB_N;
            ct[j] = cand_flat[j] % VOCAB_N;
        }
        // finalize merge: all_sc = [fin_sc, eos_norm]
        float allsc[8];
        for (int j = 0; j < 4; ++j) allsc[j] = fin_sc[sent * BEAM_N + j];
        for (int j = 0; j < 4; ++j)
            allsc[4 + j] = (ct[j] == EOS_T) ? (cand_sc[j] / (float)(step + 1)) : NEGV;
        int fsel[4]; float nfin[4];
        bool used[8] = {false,false,false,false,false,false,false,false};
        for (int b = 0; b < 4; ++b) {
            int best = -1; float bvv = 0.f;
            for (int j = 0; j < 8; ++j) {
                if (used[j]) continue;
                if (best < 0 || allsc[j] > bvv) { best = j; bvv = allsc[j]; }
            }
            used[best] = true; fsel[b] = best; nfin[b] = bvv;
        }
        // new fin_tok
        for (int b = 0; b < 4; ++b) {
            const int s = fsel[b];
            if (s < 4) {
                for (int p = 0; p < L_N; ++p) tmp_fin[b * L_N + p] = cur_fin[s * L_N + p];
            } else {
                const int bm = cb[s - 4];
                for (int p = 0; p < L_N; ++p)
                    tmp_fin[b * L_N + p] = (p == step + 1) ? EOS_T : cur_tok[bm * L_N + p];
            }
        }
        // active: first 4 non-EOS candidates in order
        int ab[4], atk[4]; float asc[4]; int na = 0;
        for (int j = 0; j < 8 && na < 4; ++j) {
            if (ct[j] != EOS_T) { ab[na] = cb[j]; atk[na] = ct[j]; asc[na] = cand_sc[j]; ++na; }
        }
        // reorder + append
        for (int b = 0; b < 4; ++b) {
            const int bm = ab[b];
            for (int p = 0; p < L_N; ++p)
                tmp_tok[b * L_N + p] = (p == step + 1) ? atk[b] : cur_tok[bm * L_N + p];
            for (int p = 0; p < SLEN_N; ++p)
                tmp_sc[b * SLEN_N + p] = (p == step) ? asc[b] : cur_sc[bm * SLEN_N + p];
        }
        for (int b = 0; b < 4; ++b) nfin_s[b] = nfin[b];
    }
    __syncthreads();

    // parallel writeback
    for (int e = tid; e < BEAM_N * L_N; e += 256) {
        fin_tok[sent * (BEAM_N * L_N) + e] = tmp_fin[e];
        tokens[sent * (BEAM_N * L_N) + e]  = tmp_tok[e];
    }
    for (int e = tid; e < BEAM_N * SLEN_N; e += 256)
        scores[sent * (BEAM_N * SLEN_N) + e] = tmp_sc[e];
    if (tid < 4) fin_sc[sent * BEAM_N + tid] = nfin_s[tid];
}

// ---------------- final forced-EOS merge + output write ----------------
__global__ __launch_bounds__(256) void k_final(const float* __restrict__ logits,
                                               const float* __restrict__ rmax,
                                               const float* __restrict__ rlse,
                                               const int* __restrict__ tokens,
                                               const float* __restrict__ scores,
                                               const int* __restrict__ fin_tok,
                                               const float* __restrict__ fin_sc,
                                               float* __restrict__ out) {
    const int sent = blockIdx.x;
    const int tid = threadIdx.x;
    __shared__ int fsel_s[4]; __shared__ float nfin_s[4];
    if (tid == 0) {
        float allsc[8];
        for (int r = 0; r < 4; ++r) {
            const int row = sent * BEAM_N + r;
            const float lpE = ((logits[(size_t)row * NPAD + EOS_T] - rmax[row]) - rlse[row]);
            allsc[r] = fin_sc[sent * BEAM_N + r];
            allsc[4 + r] = (scores[row * SLEN_N + (MAXLEN_N - 1)] + lpE) / 65.0f;
        }
        bool used[8] = {false,false,false,false,false,false,false,false};
        for (int b = 0; b < 4; ++b) {
            int best = -1; float bvv = 0.f;
            for (int j = 0; j < 8; ++j) {
                if (used[j]) continue;
                if (best < 0 || allsc[j] > bvv) { best = j; bvv = allsc[j]; }
            }
            used[best] = true; fsel_s[b] = best; nfin_s[b] = bvv;
        }
    }
    __syncthreads();
    for (int e = tid; e < BEAM_N * L_N; e += 256) {
        const int b = e / L_N, p = e % L_N;
        const int s = fsel_s[b]; int valt;
        if (s < 4) {
            valt = fin_tok[(sent * BEAM_N + s) * L_N + p];
        } else {
            const int r = s - 4;
            valt = (p == MAXLEN_N + 1) ? EOS_T : tokens[(sent * BEAM_N + r) * L_N + p];
        }
        out[(size_t)(sent * BEAM_N + b) * L_N + p] = (float)valt;
    }
    if (tid < 4) out[BSZ_N * BEAM_N * L_N + sent * BEAM_N + tid] = nfin_s[tid];
}

extern "C" void kernel_launch(void* const* d_in, const int* in_sizes, int n_in,
                              void* d_out, int out_size, void* d_ws, size_t ws_size,
                              hipStream_t stream) {
    const float* emb = (const float*)d_in[0];
    const float* W   = (const float*)d_in[1];
    const float* pos = (const float*)d_in[2];
    float* out = (float*)d_out;

    char* w = (char*)d_ws;
    float* hT     = (float*)w;  w += (size_t)DIM * BB * 4;        // 512 KB
    float* logits = (float*)w;  w += (size_t)BB * NPAD * 4;       // 25.76 MB
    float* rmaxb  = (float*)w;  w += BB * 4;
    float* rlseb  = (float*)w;  w += BB * 4;
    int*   tokens = (int*)w;    w += BB * L_N * 4;
    float* scores = (float*)w;  w += BB * SLEN_N * 4;
    int*   ftok   = (int*)w;    w += BB * L_N * 4;
    float* fsc    = (float*)w;  w += BB * 4;

    k_init<<<32, 256, 0, stream>>>(tokens, scores, ftok, fsc);
    for (int s = 0; s < MAXLEN_N; ++s) {
        k_gather<<<(DIM * BB) / 256, 256, 0, stream>>>(emb, pos, tokens, hT, s);
        k_gemm<<<NPAD / 64, 256, 0, stream>>>(W, hT, logits);
        k_rowstats<<<BB, 256, 0, stream>>>(logits, rmaxb, rlseb);
        k_topk<<<BSZ_N, 256, 0, stream>>>(logits, rmaxb, rlseb, tokens, scores, ftok, fsc, s);
    }
    k_gather<<<(DIM * BB) / 256, 256, 0, stream>>>(emb, pos, tokens, hT, MAXLEN_N);
    k_gemm<<<NPAD / 64, 256, 0, stream>>>(W, hT, logits);
    k_rowstats<<<BB, 256, 0, stream>>>(logits, rmaxb, rlseb);
    k_final<<<BSZ_N, 256, 0, stream>>>(logits, rmaxb, rlseb, tokens, scores, ftok, fsc, out);
}

// Round 5
// 38553.098 us; speedup vs baseline: 3.2569x; 2.9409x over previous
//
#include <hip/hip_runtime.h>
#include <cstdint>
#include <cstddef>

#define VOCAB_N 50257
#define NPAD    50304          // padded row stride for logits
#define DIM     1024
#define BSZ_N   32
#define BEAM_N  4
#define BB      128            // BSZ * BEAM
#define L_N     66             // MAXLEN + 2
#define SLEN_N  65             // MAXLEN + 1
#define MAXLEN_N 64
#define PAD_T   1
#define EOS_T   2
#define NEGV    (-1e9f)
#define SENTV   (-3.402823466e38f)
#define PW_BLOCK 128

// tree layout in ws (ints): [0..7]=hdr{nleaf,nint,maxlev,root}, +8 lstart[1024],
// +1032 lnum[1024], +2056 lslot[1024], +3080 eL[1024], +4104 eR[1024], +5128 eD[1024], +6152 lvl[32]
#define T_LSTART 8
#define T_LNUM   (8 + 1024)
#define T_LSLOT  (8 + 2048)
#define T_EL     (8 + 3072)
#define T_ER     (8 + 4096)
#define T_ED     (8 + 5120)
#define T_LVL    (8 + 6144)
#define T_INTS   (8 + 6144 + 32)

// ---------------- init state ----------------
__global__ void k_init(int* __restrict__ tokens, float* __restrict__ scores,
                       int* __restrict__ fin_tok, float* __restrict__ fin_sc) {
    int i = blockIdx.x * blockDim.x + threadIdx.x;
    int st = gridDim.x * blockDim.x;
    for (int k = i; k < BB * L_N; k += st) tokens[k] = ((k % L_N) == 0) ? EOS_T : PAD_T;
    for (int k = i; k < BB * SLEN_N; k += st) scores[k] = 0.f;
    for (int k = i; k < BB * L_N; k += st) fin_tok[k] = 0;
    for (int k = i; k < BB; k += st) fin_sc[k] = NEGV;
}

// ---------------- one-time: numpy pairwise tree schedule (LDS stacks, no scratch) ----------------
__global__ void k_prep(int* __restrict__ tree) {
    __shared__ int fs[64], fn[64], fst[64], fls[64], fll[64];
    __shared__ int tL[1024], tR[1024], tD[1024], tLev[1024];
    __shared__ int cl[40], pos[40];
    if (threadIdx.x != 0 || blockIdx.x != 0) return;
    int* lstart = tree + T_LSTART; int* lnum = tree + T_LNUM; int* lslot = tree + T_LSLOT;
    int* eL = tree + T_EL; int* eR = tree + T_ER; int* eD = tree + T_ED;
    int* lvl = tree + T_LVL;
    int sp = 0, lc = 0, nc = 0, cnt = 0;
    fs[0] = 0; fn[0] = VOCAB_N; fst[0] = 0; sp = 1;
    int retslot = -1, retlev = 0;
    while (sp > 0) {
        const int n = fn[sp - 1], s = fs[sp - 1], st = fst[sp - 1];
        if (n <= PW_BLOCK) {
            lstart[lc] = s; lnum[lc] = n; lslot[lc] = cnt;
            retslot = cnt; retlev = 0; ++cnt; ++lc; --sp; continue;
        }
        int L = (n >> 1); L -= (L & 7);
        if (st == 0)      { fst[sp - 1] = 1; fs[sp] = s;     fn[sp] = L;     fst[sp] = 0; ++sp; }
        else if (st == 1) { fls[sp - 1] = retslot; fll[sp - 1] = retlev; fst[sp - 1] = 2;
                            fs[sp] = s + L; fn[sp] = n - L; fst[sp] = 0; ++sp; }
        else {
            const int lv = (fll[sp - 1] > retlev ? fll[sp - 1] : retlev) + 1;
            tL[nc] = fls[sp - 1]; tR[nc] = retslot; tD[nc] = cnt; tLev[nc] = lv;
            retslot = cnt; retlev = lv; ++cnt; ++nc; --sp;
        }
    }
    int maxlev = 0;
    for (int j = 0; j < nc; ++j) if (tLev[j] > maxlev) maxlev = tLev[j];
    for (int v = 0; v <= maxlev + 1; ++v) cl[v] = 0;
    for (int j = 0; j < nc; ++j) cl[tLev[j]]++;
    int acc2 = 0;
    for (int v = 1; v <= maxlev; ++v) { lvl[v] = acc2; acc2 += cl[v]; }
    lvl[maxlev + 1] = acc2;
    for (int v = 1; v <= maxlev; ++v) pos[v] = lvl[v];
    for (int j = 0; j < nc; ++j) {
        const int v = tLev[j]; const int p = pos[v]++;
        eL[p] = tL[j]; eR[p] = tR[j]; eD[p] = tD[j];
    }
    tree[0] = lc; tree[1] = nc; tree[2] = maxlev; tree[3] = retslot;
}

// ---------------- GEMM with fused gather (f32, r1-certified chain) ----------------
#define KSTEP 16
#define FMA_ROW(i, a)                                           \
    acc[i][0] += (a) * wv.x; acc[i][1] += (a) * wv.y;           \
    acc[i][2] += (a) * wv.z; acc[i][3] += (a) * wv.w;

__global__ __launch_bounds__(256) void k_gemm(const float* __restrict__ W,
                                              const float* __restrict__ emb,
                                              const float* __restrict__ pos_emb,
                                              const int* __restrict__ tokens,
                                              float* __restrict__ logits, int step) {
    __shared__ __align__(16) float Hs[KSTEP][128];
    __shared__ __align__(16) float Ws[KSTEP][64];
    const int tid = threadIdx.x;
    const int n0 = blockIdx.x * 64;
    const int n4 = (tid & 15) * 4;
    const int m8 = (tid >> 4) * 8;
    const int lr  = tid >> 4;          // 0..15: k-row for W staging
    const int lcW = (tid & 15) * 4;
    const int mH  = tid >> 1;          // 0..127: row for H staging
    const int j0  = (tid & 1) * 8;     // 0 or 8
    const int tokH = tokens[mH * L_N + step];
    float acc[8][4];
#pragma unroll
    for (int i = 0; i < 8; ++i)
#pragma unroll
        for (int j = 0; j < 4; ++j) acc[i][j] = 0.f;

    const bool full = (n0 + 64 <= VOCAB_N);
    for (int k0 = 0; k0 < DIM; k0 += KSTEP) {
        // stage W tile [KSTEP][64]
        {
            const float* wp = W + (size_t)(k0 + lr) * VOCAB_N + n0 + lcW;
            float4 wv4;
            if (full) {
                wv4 = *(const float4*)wp;
            } else {
                wv4.x = (n0 + lcW + 0 < VOCAB_N) ? wp[0] : 0.f;
                wv4.y = (n0 + lcW + 1 < VOCAB_N) ? wp[1] : 0.f;
                wv4.z = (n0 + lcW + 2 < VOCAB_N) ? wp[2] : 0.f;
                wv4.w = (n0 + lcW + 3 < VOCAB_N) ? wp[3] : 0.f;
            }
            *(float4*)&Ws[lr][lcW] = wv4;
        }
        // stage H tile [KSTEP][128] directly from emb+pos (same single-rounded values as gather)
        {
            const float* ep = emb + (size_t)tokH * DIM + k0 + j0;
            const float* pp = pos_emb + (size_t)step * DIM + k0 + j0;
            const float4 e0 = *(const float4*)ep, e1 = *(const float4*)(ep + 4);
            const float4 p0 = *(const float4*)pp, p1 = *(const float4*)(pp + 4);
            Hs[j0 + 0][mH] = e0.x + p0.x; Hs[j0 + 1][mH] = e0.y + p0.y;
            Hs[j0 + 2][mH] = e0.z + p0.z; Hs[j0 + 3][mH] = e0.w + p0.w;
            Hs[j0 + 4][mH] = e1.x + p1.x; Hs[j0 + 5][mH] = e1.y + p1.y;
            Hs[j0 + 6][mH] = e1.z + p1.z; Hs[j0 + 7][mH] = e1.w + p1.w;
        }
        __syncthreads();
#pragma unroll
        for (int kk = 0; kk < KSTEP; ++kk) {
            const float4 wv = *(const float4*)&Ws[kk][n4];
            const float4 h0 = *(const float4*)&Hs[kk][m8];
            const float4 h1 = *(const float4*)&Hs[kk][m8 + 4];
            FMA_ROW(0, h0.x) FMA_ROW(1, h0.y) FMA_ROW(2, h0.z) FMA_ROW(3, h0.w)
            FMA_ROW(4, h1.x) FMA_ROW(5, h1.y) FMA_ROW(6, h1.z) FMA_ROW(7, h1.w)
        }
        __syncthreads();
    }
#pragma unroll
    for (int i = 0; i < 8; ++i) {
        float4 o; o.x = acc[i][0]; o.y = acc[i][1]; o.z = acc[i][2]; o.w = acc[i][3];
        *(float4*)&logits[(size_t)(m8 + i) * NPAD + n0 + n4] = o;
    }
}

// ---------------- per-thread sorted top-16 insert (stable ties by index) ----------------
__device__ __forceinline__ void ins16(float v, int ix, float tv[16], int tix[16]) {
#pragma unroll
    for (int p = 0; p < 16; ++p) {
        if (v > tv[p] || (v == tv[p] && ix < tix[p])) {
            float ov = tv[p]; int oi = tix[p];
            tv[p] = v; tix[p] = ix; v = ov; ix = oi;
        }
    }
}

// ---------------- per-row: top16 by raw logit + numpy-exact pairwise LSE ----------------
__global__ __launch_bounds__(256) void k_rowtop(const float* __restrict__ logits,
                                                const int* __restrict__ tree,
                                                float* __restrict__ cand_x,
                                                int* __restrict__ cand_ix,
                                                float* __restrict__ rmax,
                                                float* __restrict__ rlse) {
    const int row = blockIdx.x, tid = threadIdx.x;
    const float* x = logits + (size_t)row * NPAD;

    // ---- pass A: top-16 by (x, idx) ----
    float tv[16]; int tix[16];
#pragma unroll
    for (int p = 0; p < 16; ++p) { tv[p] = SENTV; tix[p] = 0x7fffffff; }
    for (int v = tid * 4; v + 3 < VOCAB_N; v += 1024) {
        const float4 t = *(const float4*)(x + v);
        float va[4] = {t.x, t.y, t.z, t.w};
#pragma unroll
        for (int u = 0; u < 4; ++u) {
            const int tk = v + u;
            if (tk == PAD_T) continue;
            if (va[u] >= tv[15]) ins16(va[u], tk, tv, tix);
        }
    }
    if (tid == 0) {
        const int tk = VOCAB_N - 1;
        if (x[tk] >= tv[15]) ins16(x[tk], tk, tv, tix);
    }

    // merge: 16 passes of stable argmax over 4096 entries
    __shared__ float sval[4096];
    __shared__ int   sidx[4096];
#pragma unroll
    for (int p = 0; p < 16; ++p) { sval[tid * 16 + p] = tv[p]; sidx[tid * 16 + p] = tix[p]; }
    __shared__ float rv[256]; __shared__ int ri[256]; __shared__ int rs[256];
    __shared__ float cand_sx[16]; __shared__ int cand_si[16];
    __syncthreads();
    for (int pass = 0; pass < 16; ++pass) {
        float bv = SENTV; int bi = 0x7fffffff; int bs = -1;
        for (int k = tid; k < 4096; k += 256) {
            const float v = sval[k]; const int ix = sidx[k];
            if (v > bv || (v == bv && ix < bi)) { bv = v; bi = ix; bs = k; }
        }
        rv[tid] = bv; ri[tid] = bi; rs[tid] = bs;
        __syncthreads();
        for (int s = 128; s > 0; s >>= 1) {
            if (tid < s) {
                if (rv[tid + s] > rv[tid] ||
                    (rv[tid + s] == rv[tid] && ri[tid + s] < ri[tid])) {
                    rv[tid] = rv[tid + s]; ri[tid] = ri[tid + s]; rs[tid] = rs[tid + s];
                }
            }
            __syncthreads();
        }
        if (tid == 0) {
            cand_sx[pass] = rv[0]; cand_si[pass] = ri[0];
            sval[rs[0]] = SENTV; sidx[rs[0]] = 0x7fffffff;
        }
        __syncthreads();
    }
    const float mrow = cand_sx[0];   // exact row max

    // ---- pass B: numpy pairwise exp-sum via precomputed tree (no scratch) ----
    __shared__ int hN[4];
    __shared__ int lvls[32];
    if (tid < 4) hN[tid] = tree[tid];
    if (tid < 32) lvls[tid] = tree[T_LVL + tid];
    __syncthreads();
    const int nleaf = hN[0], maxlev = hN[2], root = hN[3];
    const int* lstart = tree + T_LSTART; const int* lnum = tree + T_LNUM;
    const int* lslot = tree + T_LSLOT;
    const int* eL = tree + T_EL; const int* eR = tree + T_ER; const int* eD = tree + T_ED;
    __shared__ float slot[1100];
    for (int leaf = tid; leaf < nleaf; leaf += 256) {
        const int s = lstart[leaf];
        const int n = lnum[leaf];
        float res;
        if (n < 8) {
            res = 0.f;
            for (int i = 0; i < n; ++i) res += expf(x[s + i] - mrow);
        } else {
            float r0 = expf(x[s + 0] - mrow), r1 = expf(x[s + 1] - mrow);
            float r2 = expf(x[s + 2] - mrow), r3 = expf(x[s + 3] - mrow);
            float r4 = expf(x[s + 4] - mrow), r5 = expf(x[s + 5] - mrow);
            float r6 = expf(x[s + 6] - mrow), r7 = expf(x[s + 7] - mrow);
            int i = 8;
            const int lim = n - (n & 7);
            for (; i < lim; i += 8) {
                r0 += expf(x[s + i + 0] - mrow); r1 += expf(x[s + i + 1] - mrow);
                r2 += expf(x[s + i + 2] - mrow); r3 += expf(x[s + i + 3] - mrow);
                r4 += expf(x[s + i + 4] - mrow); r5 += expf(x[s + i + 5] - mrow);
                r6 += expf(x[s + i + 6] - mrow); r7 += expf(x[s + i + 7] - mrow);
            }
            res = ((r0 + r1) + (r2 + r3)) + ((r4 + r5) + (r6 + r7));
            for (; i < n; ++i) res += expf(x[s + i] - mrow);
        }
        slot[lslot[leaf]] = res;
    }
    __syncthreads();
    for (int lev = 1; lev <= maxlev; ++lev) {
        for (int j = lvls[lev] + tid; j < lvls[lev + 1]; j += 256)
            slot[eD[j]] = slot[eL[j]] + slot[eR[j]];
        __syncthreads();
    }
    if (tid == 0) {
        rmax[row] = mrow;
        rlse[row] = (float)log((double)slot[root]);
    }
    if (tid < 16) {
        cand_x[row * 16 + tid]  = cand_sx[tid];
        cand_ix[row * 16 + tid] = cand_si[tid];
    }
}

// ---------------- per-sentence: candidate vals + top-8 + literal bookkeeping ----------------
__global__ __launch_bounds__(256) void k_beam(const float* __restrict__ cand_x,
                                              const int* __restrict__ cand_ix,
                                              const float* __restrict__ rmax,
                                              const float* __restrict__ rlse,
                                              int* __restrict__ tokens,
                                              float* __restrict__ scores,
                                              int* __restrict__ fin_tok,
                                              float* __restrict__ fin_sc,
                                              int step) {
    const int sent = blockIdx.x;
    const int tid = threadIdx.x;
    const int rN = (step == 0) ? 1 : BEAM_N;
    __shared__ float bval[64]; __shared__ int bflat[64];
    if (tid < 16 * rN) {
        const int r = tid >> 4, j = tid & 15;
        const int row = sent * BEAM_N + r;
        const float rm = rmax[row], rl = rlse[row];
        const float prev = (step == 0) ? 0.f : scores[row * SLEN_N + step - 1];
        const float xv = cand_x[row * 16 + j];
        const int   tk = cand_ix[row * 16 + j];
        bval[tid]  = ((xv - rm) - rl) + prev;   // exact ref association
        bflat[tid] = r * VOCAB_N + tk;
    }
    __syncthreads();
    __shared__ float cand_sc[8]; __shared__ int cand_flat[8];
    if (tid == 0) {
        const int nC = 16 * rN;
        for (int pass = 0; pass < 8; ++pass) {
            float bv = SENTV; int bi = 0x7fffffff; int bs = -1;
            for (int k = 0; k < nC; ++k) {
                const float v = bval[k]; const int ix = bflat[k];
                if (v > bv || (v == bv && ix < bi)) { bv = v; bi = ix; bs = k; }
            }
            cand_sc[pass] = bv; cand_flat[pass] = bi;
            bval[bs] = SENTV; bflat[bs] = 0x7fffffff;
        }
    }
    __syncthreads();

    // preload sentence state into LDS (parallel)
    __shared__ int   cur_tok[BEAM_N * L_N];
    __shared__ int   cur_fin[BEAM_N * L_N];
    __shared__ float cur_sc[BEAM_N * SLEN_N];
    for (int e = tid; e < BEAM_N * L_N; e += 256) {
        cur_tok[e] = tokens[sent * (BEAM_N * L_N) + e];
        cur_fin[e] = fin_tok[sent * (BEAM_N * L_N) + e];
    }
    for (int e = tid; e < BEAM_N * SLEN_N; e += 256)
        cur_sc[e] = scores[sent * (BEAM_N * SLEN_N) + e];
    __syncthreads();

    // literal single-thread bookkeeping (mirrors the reference text)
    __shared__ int   tmp_fin[BEAM_N * L_N];
    __shared__ int   tmp_tok[BEAM_N * L_N];
    __shared__ float tmp_sc[BEAM_N * SLEN_N];
    __shared__ float nfin_s[BEAM_N];
    if (tid == 0) {
        int cb[8], ct[8];
#pragma unroll
        for (int j = 0; j < 8; ++j) {
            cb[j] = cand_flat[j] / VOCAB_N;
            ct[j] = cand_flat[j] % VOCAB_N;
        }
        float allsc[8];
#pragma unroll
        for (int j = 0; j < 4; ++j) allsc[j] = fin_sc[sent * BEAM_N + j];
#pragma unroll
        for (int j = 0; j < 4; ++j)
            allsc[4 + j] = (ct[j] == EOS_T) ? (cand_sc[j] / (float)(step + 1)) : NEGV;
        int fsel[4]; float nfin[4];
        bool used[8] = {false,false,false,false,false,false,false,false};
#pragma unroll
        for (int b = 0; b < 4; ++b) {
            int best = -1; float bvv = 0.f;
#pragma unroll
            for (int j = 0; j < 8; ++j) {
                if (used[j]) continue;
                if (best < 0 || allsc[j] > bvv) { best = j; bvv = allsc[j]; }
            }
            used[best] = true; fsel[b] = best; nfin[b] = bvv;
        }
#pragma unroll
        for (int b = 0; b < 4; ++b) {
            const int s = fsel[b];
            if (s < 4) {
                for (int p = 0; p < L_N; ++p) tmp_fin[b * L_N + p] = cur_fin[s * L_N + p];
            } else {
                const int bm = cb[s - 4];
                for (int p = 0; p < L_N; ++p)
                    tmp_fin[b * L_N + p] = (p == step + 1) ? EOS_T : cur_tok[bm * L_N + p];
            }
        }
        int ab[4], atk[4]; float asc[4]; int na = 0;
#pragma unroll
        for (int j = 0; j < 8; ++j) {
            if (na < 4 && ct[j] != EOS_T) { ab[na] = cb[j]; atk[na] = ct[j]; asc[na] = cand_sc[j]; ++na; }
        }
#pragma unroll
        for (int b = 0; b < 4; ++b) {
            const int bm = ab[b];
            for (int p = 0; p < L_N; ++p)
                tmp_tok[b * L_N + p] = (p == step + 1) ? atk[b] : cur_tok[bm * L_N + p];
            for (int p = 0; p < SLEN_N; ++p)
                tmp_sc[b * SLEN_N + p] = (p == step) ? asc[b] : cur_sc[bm * SLEN_N + p];
        }
#pragma unroll
        for (int b = 0; b < 4; ++b) nfin_s[b] = nfin[b];
    }
    __syncthreads();

    for (int e = tid; e < BEAM_N * L_N; e += 256) {
        fin_tok[sent * (BEAM_N * L_N) + e] = tmp_fin[e];
        tokens[sent * (BEAM_N * L_N) + e]  = tmp_tok[e];
    }
    for (int e = tid; e < BEAM_N * SLEN_N; e += 256)
        scores[sent * (BEAM_N * SLEN_N) + e] = tmp_sc[e];
    if (tid < 4) fin_sc[sent * BEAM_N + tid] = nfin_s[tid];
}

// ---------------- final forced-EOS merge + output write ----------------
__global__ __launch_bounds__(256) void k_final(const float* __restrict__ logits,
                                               const float* __restrict__ rmax,
                                               const float* __restrict__ rlse,
                                               const int* __restrict__ tokens,
                                               const float* __restrict__ scores,
                                               const int* __restrict__ fin_tok,
                                               const float* __restrict__ fin_sc,
                                               float* __restrict__ out) {
    const int sent = blockIdx.x;
    const int tid = threadIdx.x;
    __shared__ int fsel_s[4]; __shared__ float nfin_s[4];
    if (tid == 0) {
        float allsc[8];
#pragma unroll
        for (int r = 0; r < 4; ++r) {
            const int row = sent * BEAM_N + r;
            const float lpE = ((logits[(size_t)row * NPAD + EOS_T] - rmax[row]) - rlse[row]);
            allsc[r] = fin_sc[sent * BEAM_N + r];
            allsc[4 + r] = (scores[row * SLEN_N + (MAXLEN_N - 1)] + lpE) / 65.0f;
        }
        bool used[8] = {false,false,false,false,false,false,false,false};
#pragma unroll
        for (int b = 0; b < 4; ++b) {
            int best = -1; float bvv = 0.f;
#pragma unroll
            for (int j = 0; j < 8; ++j) {
                if (used[j]) continue;
                if (best < 0 || allsc[j] > bvv) { best = j; bvv = allsc[j]; }
            }
            used[best] = true; fsel_s[b] = best; nfin_s[b] = bvv;
        }
    }
    __syncthreads();
    for (int e = tid; e < BEAM_N * L_N; e += 256) {
        const int b = e / L_N, p = e % L_N;
        const int s = fsel_s[b]; int valt;
        if (s < 4) {
            valt = fin_tok[(sent * BEAM_N + s) * L_N + p];
        } else {
            const int r = s - 4;
            valt = (p == MAXLEN_N + 1) ? EOS_T : tokens[(sent * BEAM_N + r) * L_N + p];
        }
        out[(size_t)(sent * BEAM_N + b) * L_N + p] = (float)valt;
    }
    if (tid < 4) out[BSZ_N * BEAM_N * L_N + sent * BEAM_N + tid] = nfin_s[tid];
}

extern "C" void kernel_launch(void* const* d_in, const int* in_sizes, int n_in,
                              void* d_out, int out_size, void* d_ws, size_t ws_size,
                              hipStream_t stream) {
    const float* emb = (const float*)d_in[0];
    const float* W   = (const float*)d_in[1];
    const float* pos = (const float*)d_in[2];
    float* out = (float*)d_out;

    char* w = (char*)d_ws;
    float* logits = (float*)w;  w += (size_t)BB * NPAD * 4;       // 25.76 MB
    float* rmaxb  = (float*)w;  w += BB * 4;
    float* rlseb  = (float*)w;  w += BB * 4;
    int*   tokens = (int*)w;    w += BB * L_N * 4;
    float* scores = (float*)w;  w += BB * SLEN_N * 4;
    int*   ftok   = (int*)w;    w += BB * L_N * 4;
    float* fsc    = (float*)w;  w += BB * 4;
    float* candx  = (float*)w;  w += BB * 16 * 4;
    int*   candix = (int*)w;    w += BB * 16 * 4;
    int*   tree   = (int*)w;    w += T_INTS * 4;

    k_init<<<32, 256, 0, stream>>>(tokens, scores, ftok, fsc);
    k_prep<<<1, 64, 0, stream>>>(tree);
    for (int s = 0; s < MAXLEN_N; ++s) {
        k_gemm<<<NPAD / 64, 256, 0, stream>>>(W, emb, pos, tokens, logits, s);
        k_rowtop<<<BB, 256, 0, stream>>>(logits, tree, candx, candix, rmaxb, rlseb);
        k_beam<<<BSZ_N, 256, 0, stream>>>(candx, candix, rmaxb, rlseb, tokens, scores, ftok, fsc, s);
    }
    k_gemm<<<NPAD / 64, 256, 0, stream>>>(W, emb, pos, tokens, logits, MAXLEN_N);
    k_rowtop<<<BB, 256, 0, stream>>>(logits, tree, candx, candix, rmaxb, rlseb);
    k_final<<<BSZ_N, 256, 0, stream>>>(logits, rmaxb, rlseb, tokens, scores, ftok, fsc, out);
}

// Round 6
// 28162.744 us; speedup vs baseline: 4.4584x; 1.3689x over previous
//
#include <hip/hip_runtime.h>
#include <cstdint>
#include <cstddef>

#define VOCAB_N 50257
#define NPAD    50304          // padded row stride for logits (393 * 128)
#define DIM     1024
#define BSZ_N   32
#define BEAM_N  4
#define BB      128            // BSZ * BEAM
#define L_N     66             // MAXLEN + 2
#define SLEN_N  65             // MAXLEN + 1
#define MAXLEN_N 64
#define PAD_T   1
#define EOS_T   2
#define NEGV    (-1e9f)
#define SENTV   (-3.402823466e38f)
#define PW_BLOCK 128

// ---------------- compile-time numpy pairwise_sum tree ----------------
struct PWTree {
    int nleaf, nint, maxlev, root;
    int lstart[1024], lnum[1024], lslot[1024];
    int eL[1024], eR[1024], eD[1024];
    int lvl[32];
};

constexpr PWTree build_tree() {
    PWTree t{};
    int fs[64] = {}, fn[64] = {}, fstt[64] = {}, fls[64] = {}, fll[64] = {};
    int tL[1024] = {}, tR[1024] = {}, tD[1024] = {}, tLev[1024] = {};
    int sp = 0, lc = 0, nc = 0, cnt = 0;
    fs[0] = 0; fn[0] = VOCAB_N; fstt[0] = 0; sp = 1;
    int retslot = -1, retlev = 0;
    while (sp > 0) {
        const int n = fn[sp - 1], s = fs[sp - 1], st = fstt[sp - 1];
        if (n <= PW_BLOCK) {
            t.lstart[lc] = s; t.lnum[lc] = n; t.lslot[lc] = cnt;
            retslot = cnt; retlev = 0; ++cnt; ++lc; --sp; continue;
        }
        int L = (n >> 1); L -= (L & 7);
        if (st == 0)      { fstt[sp - 1] = 1; fs[sp] = s;     fn[sp] = L;     fstt[sp] = 0; ++sp; }
        else if (st == 1) { fls[sp - 1] = retslot; fll[sp - 1] = retlev; fstt[sp - 1] = 2;
                            fs[sp] = s + L; fn[sp] = n - L; fstt[sp] = 0; ++sp; }
        else {
            const int lv = (fll[sp - 1] > retlev ? fll[sp - 1] : retlev) + 1;
            tL[nc] = fls[sp - 1]; tR[nc] = retslot; tD[nc] = cnt; tLev[nc] = lv;
            retslot = cnt; retlev = lv; ++cnt; ++nc; --sp;
        }
    }
    int maxlev = 0;
    for (int j = 0; j < nc; ++j) if (tLev[j] > maxlev) maxlev = tLev[j];
    int cl[40] = {};
    for (int j = 0; j < nc; ++j) cl[tLev[j]]++;
    int acc = 0;
    for (int v = 1; v <= maxlev; ++v) { t.lvl[v] = acc; acc += cl[v]; }
    t.lvl[maxlev + 1] = acc;
    int pos[40] = {};
    for (int v = 1; v <= maxlev; ++v) pos[v] = t.lvl[v];
    for (int j = 0; j < nc; ++j) {
        const int v = tLev[j]; const int p = pos[v]++;
        t.eL[p] = tL[j]; t.eR[p] = tR[j]; t.eD[p] = tD[j];
    }
    t.nleaf = lc; t.nint = nc; t.maxlev = maxlev; t.root = retslot;
    return t;
}

__device__ constexpr PWTree g_tree = build_tree();

// ---------------- init state ----------------
__global__ void k_init(int* __restrict__ tokens, float* __restrict__ scores,
                       int* __restrict__ fin_tok, float* __restrict__ fin_sc) {
    int i = blockIdx.x * blockDim.x + threadIdx.x;
    int st = gridDim.x * blockDim.x;
    for (int k = i; k < BB * L_N; k += st) tokens[k] = ((k % L_N) == 0) ? EOS_T : PAD_T;
    for (int k = i; k < BB * SLEN_N; k += st) scores[k] = 0.f;
    for (int k = i; k < BB * L_N; k += st) fin_tok[k] = 0;
    for (int k = i; k < BB; k += st) fin_sc[k] = NEGV;
}

// ---------------- GEMM 128x128 tile, 8x8/thread, fused gather (r1-certified chain) ----------------
#define KSTEP 16
__global__ __launch_bounds__(256) void k_gemm(const float* __restrict__ W,
                                              const float* __restrict__ emb,
                                              const float* __restrict__ pos_emb,
                                              const int* __restrict__ tokens,
                                              float* __restrict__ logits, int step) {
    __shared__ __align__(16) float Hs[KSTEP][128];    // 8 KB
    __shared__ __align__(16) float WsP[KSTEP][192];   // 12 KB: 16 groups x 8 floats @ stride 12
    const int tid = threadIdx.x;
    const int n0 = blockIdx.x * 128;
    const int cg  = tid & 15;          // col group (8 cols)
    const int m8  = (tid >> 4) * 8;    // row group (8 rows)
    const int c12 = cg * 12;
    const int lr  = tid >> 4;          // k-row for W staging
    const int mH  = tid >> 1;          // H staging row
    const int j0  = (tid & 1) * 8;     // H staging k-offset
    const int tokH = tokens[mH * L_N + step];
    const int nb = n0 + cg * 8;
    float acc[8][8];
#pragma unroll
    for (int i = 0; i < 8; ++i)
#pragma unroll
        for (int j = 0; j < 8; ++j) acc[i][j] = 0.f;

    const bool full = (n0 + 128 <= VOCAB_N);
    for (int k0 = 0; k0 < DIM; k0 += KSTEP) {
        // stage W tile rows k0..k0+15, cols n0..n0+127
        {
            const float* wp = W + (size_t)(k0 + lr) * VOCAB_N + nb;
            float4 a, b;
            if (full) {
                a = *(const float4*)wp;
                b = *(const float4*)(wp + 4);
            } else {
                a.x = (nb + 0 < VOCAB_N) ? wp[0] : 0.f;
                a.y = (nb + 1 < VOCAB_N) ? wp[1] : 0.f;
                a.z = (nb + 2 < VOCAB_N) ? wp[2] : 0.f;
                a.w = (nb + 3 < VOCAB_N) ? wp[3] : 0.f;
                b.x = (nb + 4 < VOCAB_N) ? wp[4] : 0.f;
                b.y = (nb + 5 < VOCAB_N) ? wp[5] : 0.f;
                b.z = (nb + 6 < VOCAB_N) ? wp[6] : 0.f;
                b.w = (nb + 7 < VOCAB_N) ? wp[7] : 0.f;
            }
            *(float4*)&WsP[lr][c12]     = a;
            *(float4*)&WsP[lr][c12 + 4] = b;
        }
        // stage H tile from emb+pos (identical single-rounded values as gather)
        {
            const float* ep = emb + (size_t)tokH * DIM + k0 + j0;
            const float* pp = pos_emb + (size_t)step * DIM + k0 + j0;
            const float4 e0 = *(const float4*)ep, e1 = *(const float4*)(ep + 4);
            const float4 p0 = *(const float4*)pp, p1 = *(const float4*)(pp + 4);
            Hs[j0 + 0][mH] = e0.x + p0.x; Hs[j0 + 1][mH] = e0.y + p0.y;
            Hs[j0 + 2][mH] = e0.z + p0.z; Hs[j0 + 3][mH] = e0.w + p0.w;
            Hs[j0 + 4][mH] = e1.x + p1.x; Hs[j0 + 5][mH] = e1.y + p1.y;
            Hs[j0 + 6][mH] = e1.z + p1.z; Hs[j0 + 7][mH] = e1.w + p1.w;
        }
        __syncthreads();
#pragma unroll
        for (int kk = 0; kk < KSTEP; ++kk) {
            const float4 w0 = *(const float4*)&WsP[kk][c12];
            const float4 w1 = *(const float4*)&WsP[kk][c12 + 4];
            const float4 h0 = *(const float4*)&Hs[kk][m8];
            const float4 h1 = *(const float4*)&Hs[kk][m8 + 4];
            const float hh[8] = {h0.x, h0.y, h0.z, h0.w, h1.x, h1.y, h1.z, h1.w};
            const float ww[8] = {w0.x, w0.y, w0.z, w0.w, w1.x, w1.y, w1.z, w1.w};
#pragma unroll
            for (int i = 0; i < 8; ++i)
#pragma unroll
                for (int j = 0; j < 8; ++j)
                    acc[i][j] += hh[i] * ww[j];     // k-ascending f32 FMA chain (certified)
        }
        __syncthreads();
    }
#pragma unroll
    for (int i = 0; i < 8; ++i) {
        float4 o0; o0.x = acc[i][0]; o0.y = acc[i][1]; o0.z = acc[i][2]; o0.w = acc[i][3];
        float4 o1; o1.x = acc[i][4]; o1.y = acc[i][5]; o1.z = acc[i][6]; o1.w = acc[i][7];
        float* dst = &logits[(size_t)(m8 + i) * NPAD + nb];
        *(float4*)dst = o0;
        *(float4*)(dst + 4) = o1;
    }
}

// ---------------- packed (x, idx) keys: strict total order, stable ties ----------------
__device__ __forceinline__ unsigned sortable_f32(float x) {
    unsigned u = __float_as_uint(x);
    return (u & 0x80000000u) ? ~u : (u | 0x80000000u);
}
__device__ __forceinline__ float unsort_f32(unsigned s) {
    unsigned u = (s & 0x80000000u) ? (s & 0x7fffffffu) : ~s;
    return __uint_as_float(u);
}
__device__ __forceinline__ unsigned long long pack_key(float x, int tk) {
    return ((unsigned long long)sortable_f32(x) << 32) | (unsigned)(VOCAB_N - tk);
}
__device__ __forceinline__ void insk16(unsigned long long k, unsigned long long lst[16]) {
#pragma unroll
    for (int p = 0; p < 16; ++p) {
        if (k > lst[p]) { unsigned long long o = lst[p]; lst[p] = k; k = o; }
    }
}
__device__ __forceinline__ unsigned long long wave_max_u64(unsigned long long v) {
#pragma unroll
    for (int o = 32; o > 0; o >>= 1) {
        unsigned long long w = __shfl_xor(v, o, 64);
        if (w > v) v = w;
    }
    return v;
}

// ---------------- per-row: top16 (excl PAD) + max (incl PAD) + numpy-exact pairwise LSE ----------------
__global__ __launch_bounds__(256) void k_rowtop(const float* __restrict__ logits,
                                                float* __restrict__ cand_x,
                                                int* __restrict__ cand_ix,
                                                float* __restrict__ rmax,
                                                float* __restrict__ rlse) {
    const int row = blockIdx.x, tid = threadIdx.x;
    const int lane = tid & 63, wid = tid >> 6;
    const float* x = logits + (size_t)row * NPAD;

    // ---- scan: per-thread top-16 (excluding PAD) + running max (including PAD) ----
    unsigned long long lst[16];
#pragma unroll
    for (int p = 0; p < 16; ++p) lst[p] = 0ULL;
    float mAll = SENTV;
    for (int v = tid * 4; v + 3 < VOCAB_N; v += 1024) {
        const float4 t = *(const float4*)(x + v);
        mAll = fmaxf(mAll, fmaxf(fmaxf(t.x, t.y), fmaxf(t.z, t.w)));
        const float va[4] = {t.x, t.y, t.z, t.w};
#pragma unroll
        for (int u = 0; u < 4; ++u) {
            const int tk = v + u;
            if (tk == PAD_T) continue;
            const unsigned long long key = pack_key(va[u], tk);
            if (key > lst[15]) insk16(key, lst);
        }
    }
    if (tid == 0) {
        const int tk = VOCAB_N - 1;
        mAll = fmaxf(mAll, x[tk]);
        const unsigned long long key = pack_key(x[tk], tk);
        if (key > lst[15]) insk16(key, lst);
    }

    // ---- block max (includes PAD) ----
#pragma unroll
    for (int o = 32; o > 0; o >>= 1) mAll = fmaxf(mAll, __shfl_xor(mAll, o, 64));
    __shared__ float smx[4];
    if (lane == 0) smx[wid] = mAll;

    // ---- stage 1: per-wave top-16 via shfl tournament (no barriers) ----
    __shared__ unsigned long long wtop[4][16];
    for (int pass = 0; pass < 16; ++pass) {
        const unsigned long long cand = lst[0];
        const unsigned long long mx = wave_max_u64(cand);
        const unsigned long long ball = __ballot(cand == mx);
        const int first = __ffsll((unsigned long long)ball) - 1;
        if (lane == first) {
#pragma unroll
            for (int p = 0; p < 15; ++p) lst[p] = lst[p + 1];
            lst[15] = 0ULL;
        }
        if (lane == 0) wtop[wid][pass] = mx;
    }
    __syncthreads();

    // ---- stage 2: wave 0 merges 4x16 -> global top-16 ----
    __shared__ unsigned long long sfin[16];
    if (tid < 64) {
        const unsigned long long mine = wtop[tid >> 4][tid & 15];
        bool taken = false;
        for (int pass = 0; pass < 16; ++pass) {
            const unsigned long long cand = taken ? 0ULL : mine;
            const unsigned long long mx = wave_max_u64(cand);
            const unsigned long long ball = __ballot(cand == mx);
            const int first = __ffsll((unsigned long long)ball) - 1;
            if (tid == first) taken = true;
            if (tid == 0) sfin[pass] = mx;
        }
    }
    __syncthreads();
    const float mrow = fmaxf(fmaxf(smx[0], smx[1]), fmaxf(smx[2], smx[3]));

    // ---- numpy pairwise exp-sum via compile-time tree (bit-exact r3/r4 structure) ----
    __shared__ float slot[2048];
    const int nleaf = g_tree.nleaf, maxlev = g_tree.maxlev;
    for (int leaf = tid; leaf < nleaf; leaf += 256) {
        const int s = g_tree.lstart[leaf];
        const int n = g_tree.lnum[leaf];
        float res;
        if (n < 8) {
            res = 0.f;
            for (int i = 0; i < n; ++i) res += expf(x[s + i] - mrow);
        } else {
            float r0 = expf(x[s + 0] - mrow), r1 = expf(x[s + 1] - mrow);
            float r2 = expf(x[s + 2] - mrow), r3 = expf(x[s + 3] - mrow);
            float r4 = expf(x[s + 4] - mrow), r5 = expf(x[s + 5] - mrow);
            float r6 = expf(x[s + 6] - mrow), r7 = expf(x[s + 7] - mrow);
            int i = 8;
            const int lim = n - (n & 7);
            for (; i < lim; i += 8) {
                r0 += expf(x[s + i + 0] - mrow); r1 += expf(x[s + i + 1] - mrow);
                r2 += expf(x[s + i + 2] - mrow); r3 += expf(x[s + i + 3] - mrow);
                r4 += expf(x[s + i + 4] - mrow); r5 += expf(x[s + i + 5] - mrow);
                r6 += expf(x[s + i + 6] - mrow); r7 += expf(x[s + i + 7] - mrow);
            }
            res = ((r0 + r1) + (r2 + r3)) + ((r4 + r5) + (r6 + r7));
            for (; i < n; ++i) res += expf(x[s + i] - mrow);
        }
        slot[g_tree.lslot[leaf]] = res;
    }
    __syncthreads();
    for (int lev = 1; lev <= maxlev; ++lev) {
        for (int j = g_tree.lvl[lev] + tid; j < g_tree.lvl[lev + 1]; j += 256)
            slot[g_tree.eD[j]] = slot[g_tree.eL[j]] + slot[g_tree.eR[j]];
        __syncthreads();
    }
    if (tid == 0) {
        rmax[row] = mrow;
        rlse[row] = (float)log((double)slot[g_tree.root]);
    }
    if (tid < 16) {
        const unsigned long long k = sfin[tid];
        cand_x[row * 16 + tid]  = unsort_f32((unsigned)(k >> 32));
        cand_ix[row * 16 + tid] = VOCAB_N - (int)(k & 0xFFFFFFFFu);
    }
}

// ---------------- per-sentence: candidate vals + top-8 + literal bookkeeping ----------------
__global__ __launch_bounds__(256) void k_beam(const float* __restrict__ cand_x,
                                              const int* __restrict__ cand_ix,
                                              const float* __restrict__ rmax,
                                              const float* __restrict__ rlse,
                                              int* __restrict__ tokens,
                                              float* __restrict__ scores,
                                              int* __restrict__ fin_tok,
                                              float* __restrict__ fin_sc,
                                              int step) {
    const int sent = blockIdx.x;
    const int tid = threadIdx.x;
    const int rN = (step == 0) ? 1 : BEAM_N;
    __shared__ float bval[64]; __shared__ int bflat[64];
    if (tid < 16 * rN) {
        const int r = tid >> 4, j = tid & 15;
        const int row = sent * BEAM_N + r;
        const float rm = rmax[row], rl = rlse[row];
        const float prev = (step == 0) ? 0.f : scores[row * SLEN_N + step - 1];
        const float xv = cand_x[row * 16 + j];
        const int   tk = cand_ix[row * 16 + j];
        bval[tid]  = ((xv - rm) - rl) + prev;   // exact ref association
        bflat[tid] = r * VOCAB_N + tk;
    }
    __syncthreads();
    __shared__ float cand_sc[8]; __shared__ int cand_flat[8];
    if (tid == 0) {
        const int nC = 16 * rN;
        for (int pass = 0; pass < 8; ++pass) {
            float bv = SENTV; int bi = 0x7fffffff; int bs = -1;
            for (int k = 0; k < nC; ++k) {
                const float v = bval[k]; const int ix = bflat[k];
                if (v > bv || (v == bv && ix < bi)) { bv = v; bi = ix; bs = k; }
            }
            cand_sc[pass] = bv; cand_flat[pass] = bi;
            bval[bs] = SENTV; bflat[bs] = 0x7fffffff;
        }
    }
    __syncthreads();

    __shared__ int   cur_tok[BEAM_N * L_N];
    __shared__ int   cur_fin[BEAM_N * L_N];
    __shared__ float cur_sc[BEAM_N * SLEN_N];
    for (int e = tid; e < BEAM_N * L_N; e += 256) {
        cur_tok[e] = tokens[sent * (BEAM_N * L_N) + e];
        cur_fin[e] = fin_tok[sent * (BEAM_N * L_N) + e];
    }
    for (int e = tid; e < BEAM_N * SLEN_N; e += 256)
        cur_sc[e] = scores[sent * (BEAM_N * SLEN_N) + e];
    __syncthreads();

    __shared__ int   tmp_fin[BEAM_N * L_N];
    __shared__ int   tmp_tok[BEAM_N * L_N];
    __shared__ float tmp_sc[BEAM_N * SLEN_N];
    __shared__ float nfin_s[BEAM_N];
    if (tid == 0) {
        int cb[8], ct[8];
#pragma unroll
        for (int j = 0; j < 8; ++j) {
            cb[j] = cand_flat[j] / VOCAB_N;
            ct[j] = cand_flat[j] % VOCAB_N;
        }
        float allsc[8];
#pragma unroll
        for (int j = 0; j < 4; ++j) allsc[j] = fin_sc[sent * BEAM_N + j];
#pragma unroll
        for (int j = 0; j < 4; ++j)
            allsc[4 + j] = (ct[j] == EOS_T) ? (cand_sc[j] / (float)(step + 1)) : NEGV;
        int fsel[4]; float nfin[4];
        bool used[8] = {false,false,false,false,false,false,false,false};
#pragma unroll
        for (int b = 0; b < 4; ++b) {
            int best = -1; float bvv = 0.f;
#pragma unroll
            for (int j = 0; j < 8; ++j) {
                if (used[j]) continue;
                if (best < 0 || allsc[j] > bvv) { best = j; bvv = allsc[j]; }
            }
            used[best] = true; fsel[b] = best; nfin[b] = bvv;
        }
#pragma unroll
        for (int b = 0; b < 4; ++b) {
            const int s = fsel[b];
            if (s < 4) {
                for (int p = 0; p < L_N; ++p) tmp_fin[b * L_N + p] = cur_fin[s * L_N + p];
            } else {
                const int bm = cb[s - 4];
                for (int p = 0; p < L_N; ++p)
                    tmp_fin[b * L_N + p] = (p == step + 1) ? EOS_T : cur_tok[bm * L_N + p];
            }
        }
        int ab[4], atk[4]; float asc[4]; int na = 0;
#pragma unroll
        for (int j = 0; j < 8; ++j) {
            if (na < 4 && ct[j] != EOS_T) { ab[na] = cb[j]; atk[na] = ct[j]; asc[na] = cand_sc[j]; ++na; }
        }
#pragma unroll
        for (int b = 0; b < 4; ++b) {
            const int bm = ab[b];
            for (int p = 0; p < L_N; ++p)
                tmp_tok[b * L_N + p] = (p == step + 1) ? atk[b] : cur_tok[bm * L_N + p];
            for (int p = 0; p < SLEN_N; ++p)
                tmp_sc[b * SLEN_N + p] = (p == step) ? asc[b] : cur_sc[bm * SLEN_N + p];
        }
#pragma unroll
        for (int b = 0; b < 4; ++b) nfin_s[b] = nfin[b];
    }
    __syncthreads();

    for (int e = tid; e < BEAM_N * L_N; e += 256) {
        fin_tok[sent * (BEAM_N * L_N) + e] = tmp_fin[e];
        tokens[sent * (BEAM_N * L_N) + e]  = tmp_tok[e];
    }
    for (int e = tid; e < BEAM_N * SLEN_N; e += 256)
        scores[sent * (BEAM_N * SLEN_N) + e] = tmp_sc[e];
    if (tid < 4) fin_sc[sent * BEAM_N + tid] = nfin_s[tid];
}

// ---------------- final forced-EOS merge + output write ----------------
__global__ __launch_bounds__(256) void k_final(const float* __restrict__ logits,
                                               const float* __restrict__ rmax,
                                               const float* __restrict__ rlse,
                                               const int* __restrict__ tokens,
                                               const float* __restrict__ scores,
                                               const int* __restrict__ fin_tok,
                                               const float* __restrict__ fin_sc,
                                               float* __restrict__ out) {
    const int sent = blockIdx.x;
    const int tid = threadIdx.x;
    __shared__ int fsel_s[4]; __shared__ float nfin_s[4];
    if (tid == 0) {
        float allsc[8];
#pragma unroll
        for (int r = 0; r < 4; ++r) {
            const int row = sent * BEAM_N + r;
            const float lpE = ((logits[(size_t)row * NPAD + EOS_T] - rmax[row]) - rlse[row]);
            allsc[r] = fin_sc[sent * BEAM_N + r];
            allsc[4 + r] = (scores[row * SLEN_N + (MAXLEN_N - 1)] + lpE) / 65.0f;
        }
        bool used[8] = {false,false,false,false,false,false,false,false};
#pragma unroll
        for (int b = 0; b < 4; ++b) {
            int best = -1; float bvv = 0.f;
#pragma unroll
            for (int j = 0; j < 8; ++j) {
                if (used[j]) continue;
                if (best < 0 || allsc[j] > bvv) { best = j; bvv = allsc[j]; }
            }
            used[best] = true; fsel_s[b] = best; nfin_s[b] = bvv;
        }
    }
    __syncthreads();
    for (int e = tid; e < BEAM_N * L_N; e += 256) {
        const int b = e / L_N, p = e % L_N;
        const int s = fsel_s[b]; int valt;
        if (s < 4) {
            valt = fin_tok[(sent * BEAM_N + s) * L_N + p];
        } else {
            const int r = s - 4;
            valt = (p == MAXLEN_N + 1) ? EOS_T : tokens[(sent * BEAM_N + r) * L_N + p];
        }
        out[(size_t)(sent * BEAM_N + b) * L_N + p] = (float)valt;
    }
    if (tid < 4) out[BSZ_N * BEAM_N * L_N + sent * BEAM_N + tid] = nfin_s[tid];
}

extern "C" void kernel_launch(void* const* d_in, const int* in_sizes, int n_in,
                              void* d_out, int out_size, void* d_ws, size_t ws_size,
                              hipStream_t stream) {
    const float* emb = (const float*)d_in[0];
    const float* W   = (const float*)d_in[1];
    const float* pos = (const float*)d_in[2];
    float* out = (float*)d_out;

    char* w = (char*)d_ws;
    float* logits = (float*)w;  w += (size_t)BB * NPAD * 4;       // 25.76 MB
    float* rmaxb  = (float*)w;  w += BB * 4;
    float* rlseb  = (float*)w;  w += BB * 4;
    int*   tokens = (int*)w;    w += BB * L_N * 4;
    float* scores = (float*)w;  w += BB * SLEN_N * 4;
    int*   ftok   = (int*)w;    w += BB * L_N * 4;
    float* fsc    = (float*)w;  w += BB * 4;
    float* candx  = (float*)w;  w += BB * 16 * 4;
    int*   candix = (int*)w;    w += BB * 16 * 4;

    k_init<<<32, 256, 0, stream>>>(tokens, scores, ftok, fsc);
    for (int s = 0; s < MAXLEN_N; ++s) {
        k_gemm<<<NPAD / 128, 256, 0, stream>>>(W, emb, pos, tokens, logits, s);
        k_rowtop<<<BB, 256, 0, stream>>>(logits, candx, candix, rmaxb, rlseb);
        k_beam<<<BSZ_N, 256, 0, stream>>>(candx, candix, rmaxb, rlseb, tokens, scores, ftok, fsc, s);
    }
    k_gemm<<<NPAD / 128, 256, 0, stream>>>(W, emb, pos, tokens, logits, MAXLEN_N);
    k_rowtop<<<BB, 256, 0, stream>>>(logits, candx, candix, rmaxb, rlseb);
    k_final<<<BSZ_N, 256, 0, stream>>>(logits, rmaxb, rlseb, tokens, scores, ftok, fsc, out);
}